// Round 5
// baseline (622.294 us; speedup 1.0000x reference)
//
#include <hip/hip_runtime.h>
#include <hip/hip_bf16.h>

// ShiftWindowMSA fused pipeline for MI355X (gfx950).
// R5: hardware bf16 conversion (v_cvt_pk_bf16_f32) everywhere hot;
// operand-swapped MFMA for k/q/proj so epilogue stores vectorize (8/16B);
// v stored direct (no LDS transpose) -> gemm_qkv LDS 36864->32768 B;
// q-scale folded into prepped W_skip.

typedef __attribute__((ext_vector_type(8))) short short8;
typedef __attribute__((ext_vector_type(4))) float floatx4;

#define MFMA16(a, b, c) __builtin_amdgcn_mfma_f32_16x16x32_bf16(a, b, c, 0, 0, 0)

__device__ __forceinline__ short f2bf(float f) {
    __hip_bfloat16 h = __float2bfloat16(f);
    return *reinterpret_cast<short*>(&h);
}

// packed fp32->bf16 RNE: D[15:0]=bf16(lo), D[31:16]=bf16(hi)
__device__ __forceinline__ unsigned cvt2bf(float lo, float hi) {
    unsigned r;
    asm("v_cvt_pk_bf16_f32 %0, %1, %2" : "=v"(r) : "v"(lo), "v"(hi));
    return r;
}

__device__ __forceinline__ void glds16(const void* g, void* l) {
    __builtin_amdgcn_global_load_lds(
        (const __attribute__((address_space(1))) void*)g,
        (__attribute__((address_space(3))) void*)l, 16, 0, 0);
}

// ---------------- prep kernels ----------------

// Wt[1152][384] bf16: rows 0..767 = cols of W_qkv; 768.. = cols of W_skip * SCALE
__global__ __launch_bounds__(256) void prep_wt(const float* __restrict__ Wqkv,
                                               const float* __restrict__ Wskip,
                                               short* __restrict__ Wt) {
    int tid = blockIdx.x * 256 + threadIdx.x;  // 384*144 = 55296
    if (tid >= 384 * 144) return;
    int k = tid / 144;
    int n8 = (tid % 144) * 8;
#pragma unroll
    for (int e = 0; e < 8; e++) {
        int n = n8 + e;
        float v = (n < 768) ? Wqkv[k * 768 + n]
                            : Wskip[k * 384 + (n - 768)] * 0.17677669529663687f;
        Wt[(size_t)n * 384 + k] = f2bf(v);
    }
}

__global__ __launch_bounds__(256) void prep_wtp(const float* __restrict__ Wproj,
                                                short* __restrict__ WtP) {
    int tid = blockIdx.x * 256 + threadIdx.x;  // 384*48 = 18432
    if (tid >= 384 * 48) return;
    int k = tid / 48;
    int n8 = (tid % 48) * 8;
#pragma unroll
    for (int e = 0; e < 8; e++) {
        int n = n8 + e;
        WtP[(size_t)n * 384 + k] = f2bf(Wproj[k * 384 + n]);
    }
}

// bias64[h][i][kk] = rpb_table[r(i) + r(63-kk)][h],  r(t) = 15*(t>>3) + (t&7)
__global__ __launch_bounds__(256) void prep_bias(const float* __restrict__ rpb,
                                                 float* __restrict__ bias64) {
    int tid = blockIdx.x * 256 + threadIdx.x;  // 12*64*64 = 49152
    if (tid >= 49152) return;
    int h = tid >> 12;
    int rem = tid & 4095;
    int i = rem >> 6, kk = rem & 63;
    int j = 63 - kk;
    int ridx = 15 * (i >> 3) + (i & 7) + 15 * (j >> 3) + (j & 7);
    bias64[tid] = rpb[ridx * 12 + h];
}

// ---------------- gemm_qkv ----------------
// n-blocks 0..2 -> k (swapped MFMA), 3..5 -> v (unswapped), 6..8 -> q (swapped).
__global__ __launch_bounds__(256) void gemm_qkv(
    const float* __restrict__ xq, const float* __restrict__ xs,
    const short* __restrict__ Wt,
    const float* __restrict__ bqkv, const float* __restrict__ bskip,
    short* __restrict__ kbuf, short* __restrict__ vtbuf, short* __restrict__ qbuf) {
    __shared__ short smem[16384];  // A dbuf [0,8192), B dbuf [8192,16384) shorts

    int bid = blockIdx.x;
    int per = gridDim.x >> 3;               // grid % 8 == 0
    int lb = (bid & 7) * per + (bid >> 3);  // XCD-contiguous remap
    int mblk = lb / 9, nb = lb % 9;
    int m0 = mblk * 128, n0 = nb * 128;
    const float* src = (nb < 6) ? xq : xs;
    bool isv = (nb >= 3 && nb < 6);

    int tid = threadIdx.x;
    int lane = tid & 63, wid = tid >> 6;
    int l15 = lane & 15, g4 = lane >> 4;
    int wm = wid >> 1, wn = wid & 1;

    // A staging: thread handles 2 chunks (row, slot), 8 fp32 -> 8 bf16
    const float* aptr[2];
    int awoff[2];
#pragma unroll
    for (int i = 0; i < 2; i++) {
        int cid = tid + 256 * i;
        int row = cid >> 2, slot = cid & 3;
        int sw = (row ^ (row >> 2)) & 3;
        int g = m0 + row;
        int win = g >> 6, t = g & 63;
        int b = win / 144, wr = win % 144;
        int wy = wr / 12, wx = wr % 12;
        int yy = wy * 8 + (t >> 3) + 4; if (yy >= 96) yy -= 96;
        int xx = wx * 8 + (t & 7) + 4;  if (xx >= 96) xx -= 96;
        aptr[i] = src + ((size_t)b * 9216 + yy * 96 + xx) * 384 + slot * 8;
        awoff[i] = row * 32 + ((slot ^ sw) * 8);
    }

    // B gload_lds: per wave 2 issues of 64 lanes x 16B; pre-swizzled global addr
    const short* bg[2];
    int bldsoff[2];
#pragma unroll
    for (int j = 0; j < 2; j++) {
        int c0 = wid * 128 + j * 64;
        int c = c0 + lane;
        int brow = c >> 2, bs = c & 3;
        int sw = (brow ^ (brow >> 2)) & 3;
        bg[j] = Wt + (size_t)(n0 + brow) * 384 + ((bs ^ sw) * 8);
        bldsoff[j] = 8192 + c0 * 8;
    }

    int swr = (l15 ^ (l15 >> 2)) & 3;
    int xcol = (g4 ^ swr) * 8;
    int aro[4], bro[4];
#pragma unroll
    for (int mi = 0; mi < 4; mi++) aro[mi] = (wm * 64 + mi * 16 + l15) * 32 + xcol;
#pragma unroll
    for (int nj = 0; nj < 4; nj++) bro[nj] = 8192 + (wn * 64 + nj * 16 + l15) * 32 + xcol;

    floatx4 acc[4][4];
#pragma unroll
    for (int a = 0; a < 4; a++)
#pragma unroll
        for (int b = 0; b < 4; b++)
#pragma unroll
            for (int r = 0; r < 4; r++) acc[a][b][r] = 0.f;

    // prologue: stage k-tile 0 into buffer half 0
#pragma unroll
    for (int j = 0; j < 2; j++) glds16(bg[j], smem + bldsoff[j]);
    float4 fa[2][2];
#pragma unroll
    for (int i = 0; i < 2; i++) {
        fa[i][0] = *(const float4*)(aptr[i]);
        fa[i][1] = *(const float4*)(aptr[i] + 4);
    }
#pragma unroll
    for (int i = 0; i < 2; i++) {
        uint4 u;
        u.x = cvt2bf(fa[i][0].x, fa[i][0].y);
        u.y = cvt2bf(fa[i][0].z, fa[i][0].w);
        u.z = cvt2bf(fa[i][1].x, fa[i][1].y);
        u.w = cvt2bf(fa[i][1].z, fa[i][1].w);
        *(uint4*)(smem + awoff[i]) = u;
    }
    __syncthreads();

    for (int kt = 0; kt < 12; ++kt) {
        int curb = (kt & 1) * 4096;
        int nxtb = 4096 - curb;
        bool more = kt < 11;
        if (more) {
            int k0 = (kt + 1) * 32;
#pragma unroll
            for (int j = 0; j < 2; j++) glds16(bg[j] + k0, smem + nxtb + bldsoff[j]);
#pragma unroll
            for (int i = 0; i < 2; i++) {
                fa[i][0] = *(const float4*)(aptr[i] + k0);
                fa[i][1] = *(const float4*)(aptr[i] + k0 + 4);
            }
        }
        short8 af[4], bfr[4];
#pragma unroll
        for (int mi = 0; mi < 4; mi++) af[mi] = *(const short8*)(smem + curb + aro[mi]);
#pragma unroll
        for (int nj = 0; nj < 4; nj++) bfr[nj] = *(const short8*)(smem + curb + bro[nj]);
        if (isv) {
#pragma unroll
            for (int mi = 0; mi < 4; mi++)
#pragma unroll
                for (int nj = 0; nj < 4; nj++)
                    acc[mi][nj] = MFMA16(af[mi], bfr[nj], acc[mi][nj]);
        } else {
#pragma unroll
            for (int a = 0; a < 4; a++)
#pragma unroll
                for (int b = 0; b < 4; b++)
                    acc[a][b] = MFMA16(bfr[a], af[b], acc[a][b]);
        }
        if (more) {
#pragma unroll
            for (int i = 0; i < 2; i++) {
                uint4 u;
                u.x = cvt2bf(fa[i][0].x, fa[i][0].y);
                u.y = cvt2bf(fa[i][0].z, fa[i][0].w);
                u.z = cvt2bf(fa[i][1].x, fa[i][1].y);
                u.w = cvt2bf(fa[i][1].z, fa[i][1].w);
                *(uint4*)(smem + nxtb + awoff[i]) = u;
            }
        }
        __syncthreads();
    }

    // ---- epilogue ----
    int winA = (m0 + wm * 64) >> 6;   // one window per wave
    int ncol0 = n0 + wn * 64;

    if (!isv) {
        // k or q, swapped acc: value(a,b,r) at n = ncol0+a*16+g4*4+r, t = b*16+l15
        short* buf;
        const float* bias;
        float scl;
        if (nb < 3) { buf = kbuf; bias = bqkv; scl = 1.0f; }
        else        { buf = qbuf; bias = bskip; scl = 0.17677669529663687f; }
#pragma unroll
        for (int a = 0; a < 4; a++) {
            int nbase = ncol0 + a * 16 + g4 * 4;
            int nm = (nb < 3) ? nbase : (nbase - 768);
            int head = nm >> 5, d0 = nm & 31;
            float4 bv = *(const float4*)(bias + nm);
            short* dst = buf + (size_t)(winA * 12 + head) * 2048 + d0;
#pragma unroll
            for (int b = 0; b < 4; b++) {
                int t = b * 16 + l15;
                uint2 pk;
                pk.x = cvt2bf(acc[a][b][0] + bv.x * scl, acc[a][b][1] + bv.y * scl);
                pk.y = cvt2bf(acc[a][b][2] + bv.z * scl, acc[a][b][3] + bv.w * scl);
                *(uint2*)(dst + (size_t)t * 32) = pk;
            }
        }
    } else {
        // v, unswapped acc: value(mi,nj,r) at t = mi*16+g4*4+r, col c = nj*16+l15
#pragma unroll
        for (int nj = 0; nj < 4; nj++) {
            int nm = ncol0 + nj * 16 + l15 - 384;
            int head = nm >> 5, d = nm & 31;
            float bvs = bqkv[384 + nm];
            short* dst = vtbuf + ((size_t)(winA * 12 + head) * 32 + d) * 64;
#pragma unroll
            for (int mi = 0; mi < 4; mi++) {
                int t0 = mi * 16 + g4 * 4;
                uint2 pk;
                pk.x = cvt2bf(acc[mi][nj][0] + bvs, acc[mi][nj][1] + bvs);
                pk.y = cvt2bf(acc[mi][nj][2] + bvs, acc[mi][nj][3] + bvs);
                *(uint2*)(dst + t0) = pk;
            }
        }
    }
}

// ---------------- attention ----------------
__global__ __launch_bounds__(256) void attn_kernel(
    const short* __restrict__ kbuf, const short* __restrict__ vtbuf,
    const short* __restrict__ qbuf, const float* __restrict__ bias64,
    short* __restrict__ aout, int ntask) {
    __shared__ short lps[18432];  // 4 waves x 64 x 72
    int lane = threadIdx.x & 63, wid = threadIdx.x >> 6;
    int task = blockIdx.x * 4 + wid;
    if (task >= ntask) return;
    int win = task / 12, head = task % 12;
    int l15 = lane & 15, g4 = lane >> 4;

    const short* kb = kbuf + (size_t)task * 2048;
    const short* qb = qbuf + (size_t)task * 2048;
    const short* vb = vtbuf + (size_t)task * 2048;

    short8 kf[4], qf[4], vf[2][2];
#pragma unroll
    for (int mi = 0; mi < 4; mi++)
        kf[mi] = *(const short8*)(kb + (mi * 16 + l15) * 32 + g4 * 8);
#pragma unroll
    for (int nj = 0; nj < 4; nj++)
        qf[nj] = *(const short8*)(qb + (nj * 16 + l15) * 32 + g4 * 8);
#pragma unroll
    for (int ma = 0; ma < 2; ma++)
#pragma unroll
        for (int ks = 0; ks < 2; ks++)
            vf[ma][ks] = *(const short8*)(vb + (ma * 16 + l15) * 64 + ks * 32 + g4 * 8);

    floatx4 st[4][4];
#pragma unroll
    for (int mi = 0; mi < 4; mi++)
#pragma unroll
        for (int nj = 0; nj < 4; nj++)
#pragma unroll
            for (int r = 0; r < 4; r++) st[mi][nj][r] = 0.f;

#pragma unroll
    for (int mi = 0; mi < 4; mi++)
#pragma unroll
        for (int nj = 0; nj < 4; nj++)
            st[mi][nj] = MFMA16(kf[mi], qf[nj], st[mi][nj]);  // S^T[kk][i]

    const float* bb = bias64 + head * 4096;
#pragma unroll
    for (int nj = 0; nj < 4; nj++) {
        int i = nj * 16 + l15;
#pragma unroll
        for (int mi = 0; mi < 4; mi++) {
            floatx4 b4 = *(const floatx4*)(bb + i * 64 + mi * 16 + g4 * 4);
            st[mi][nj] += b4;
        }
    }

    int wr = win % 144;
    int wy = wr / 12, wx = wr % 12;
    if (wy == 11 || wx == 11) {
        int wy11 = (wy == 11), wx11 = (wx == 11);
        int ri[4];
#pragma unroll
        for (int nj = 0; nj < 4; nj++) {
            int t = nj * 16 + l15;
            int hh = wy11 ? (((t >> 3) >= 4) ? 2 : 1) : 0;
            int ww = wx11 ? (((t & 7) >= 4) ? 2 : 1) : 0;
            ri[nj] = hh * 3 + ww;
        }
#pragma unroll
        for (int mi = 0; mi < 4; mi++)
#pragma unroll
            for (int r = 0; r < 4; r++) {
                int t = mi * 16 + g4 * 4 + r;
                int hh = wy11 ? (((t >> 3) >= 4) ? 2 : 1) : 0;
                int ww = wx11 ? (((t & 7) >= 4) ? 2 : 1) : 0;
                int rk = hh * 3 + ww;
#pragma unroll
                for (int nj = 0; nj < 4; nj++)
                    if (rk != ri[nj]) st[mi][nj][r] -= 100.0f;
            }
    }

    float rden[4];
#pragma unroll
    for (int nj = 0; nj < 4; nj++) {
        float m = -1e30f;
#pragma unroll
        for (int mi = 0; mi < 4; mi++)
#pragma unroll
            for (int r = 0; r < 4; r++) m = fmaxf(m, st[mi][nj][r]);
        m = fmaxf(m, __shfl_xor(m, 16));
        m = fmaxf(m, __shfl_xor(m, 32));
        float s = 0.f;
#pragma unroll
        for (int mi = 0; mi < 4; mi++)
#pragma unroll
            for (int r = 0; r < 4; r++) {
                float p = __expf(st[mi][nj][r] - m);
                st[mi][nj][r] = p;
                s += p;
            }
        s += __shfl_xor(s, 16);
        s += __shfl_xor(s, 32);
        rden[nj] = 1.0f / s;
    }

    // P^T -> LDS (bf16 via cvt_pk)
    short* Lp = lps + wid * 4608;  // [64][72]
#pragma unroll
    for (int mi = 0; mi < 4; mi++)
#pragma unroll
        for (int nj = 0; nj < 4; nj++) {
            uint2 pk;
            pk.x = cvt2bf(st[mi][nj][0], st[mi][nj][1]);
            pk.y = cvt2bf(st[mi][nj][2], st[mi][nj][3]);
            *(uint2*)(Lp + (nj * 16 + l15) * 72 + mi * 16 + g4 * 4) = pk;
        }

    floatx4 o[2][4];
#pragma unroll
    for (int ma = 0; ma < 2; ma++)
#pragma unroll
        for (int nj = 0; nj < 4; nj++)
#pragma unroll
            for (int r = 0; r < 4; r++) o[ma][nj][r] = 0.f;
#pragma unroll
    for (int ks = 0; ks < 2; ks++) {
        short8 pb[4];
#pragma unroll
        for (int nj = 0; nj < 4; nj++)
            pb[nj] = *(const short8*)(Lp + (nj * 16 + l15) * 72 + ks * 32 + g4 * 8);
#pragma unroll
        for (int ma = 0; ma < 2; ma++)
#pragma unroll
            for (int nj = 0; nj < 4; nj++)
                o[ma][nj] = MFMA16(vf[ma][ks], pb[nj], o[ma][nj]);
    }

    short* ob = aout + (size_t)win * 64 * 384 + head * 32;
#pragma unroll
    for (int ma = 0; ma < 2; ma++)
#pragma unroll
        for (int nj = 0; nj < 4; nj++) {
            int i = nj * 16 + l15;
            uint2 pk;
            pk.x = cvt2bf(o[ma][nj][0] * rden[nj], o[ma][nj][1] * rden[nj]);
            pk.y = cvt2bf(o[ma][nj][2] * rden[nj], o[ma][nj][3] * rden[nj]);
            *(uint2*)(ob + (size_t)i * 384 + ma * 16 + g4 * 4) = pk;
        }
}

// ---------------- gemm_proj ----------------
// Swapped MFMA everywhere: acc[a][b] at n = n0+wn*64+a*16+g4*4+r, t = b*16+l15.
__global__ __launch_bounds__(256) void gemm_proj(
    const short* __restrict__ aout, const short* __restrict__ WtP,
    const float* __restrict__ bproj, float* __restrict__ out) {
    __shared__ short smem[16384];  // A dbuf [0,8192), B dbuf [8192,16384)

    int bid = blockIdx.x;
    int per = gridDim.x >> 3;
    int lb = (bid & 7) * per + (bid >> 3);
    int mblk = lb / 3, nb = lb % 3;
    int m0 = mblk * 128, n0 = nb * 128;

    int tid = threadIdx.x;
    int lane = tid & 63, wid = tid >> 6;
    int l15 = lane & 15, g4 = lane >> 4;
    int wm = wid >> 1, wn = wid & 1;

    const short* ag[2];
    const short* bg[2];
    int ldso[2];
#pragma unroll
    for (int j = 0; j < 2; j++) {
        int c0 = wid * 128 + j * 64;
        int c = c0 + lane;
        int row = c >> 2, s = c & 3;
        int sw = (row ^ (row >> 2)) & 3;
        int co = (s ^ sw) * 8;
        ag[j] = aout + (size_t)(m0 + row) * 384 + co;
        bg[j] = WtP + (size_t)(n0 + row) * 384 + co;
        ldso[j] = c0 * 8;
    }

    int swr = (l15 ^ (l15 >> 2)) & 3;
    int xcol = (g4 ^ swr) * 8;
    int aro[4], bro[4];
#pragma unroll
    for (int mi = 0; mi < 4; mi++) aro[mi] = (wm * 64 + mi * 16 + l15) * 32 + xcol;
#pragma unroll
    for (int nj = 0; nj < 4; nj++) bro[nj] = 8192 + (wn * 64 + nj * 16 + l15) * 32 + xcol;

    floatx4 acc[4][4];
#pragma unroll
    for (int a = 0; a < 4; a++)
#pragma unroll
        for (int b = 0; b < 4; b++)
#pragma unroll
            for (int r = 0; r < 4; r++) acc[a][b][r] = 0.f;

#pragma unroll
    for (int j = 0; j < 2; j++) {
        glds16(ag[j], smem + ldso[j]);
        glds16(bg[j], smem + 8192 + ldso[j]);
    }
    __syncthreads();

    for (int kt = 0; kt < 12; ++kt) {
        int curb = (kt & 1) * 4096;
        int nxtb = 4096 - curb;
        if (kt < 11) {
            int k0 = (kt + 1) * 32;
#pragma unroll
            for (int j = 0; j < 2; j++) {
                glds16(ag[j] + k0, smem + nxtb + ldso[j]);
                glds16(bg[j] + k0, smem + 8192 + nxtb + ldso[j]);
            }
        }
        short8 af[4], bfr[4];
#pragma unroll
        for (int mi = 0; mi < 4; mi++) af[mi] = *(const short8*)(smem + curb + aro[mi]);
#pragma unroll
        for (int nj = 0; nj < 4; nj++) bfr[nj] = *(const short8*)(smem + curb + bro[nj]);
#pragma unroll
        for (int a = 0; a < 4; a++)
#pragma unroll
            for (int b = 0; b < 4; b++)
                acc[a][b] = MFMA16(bfr[a], af[b], acc[a][b]);
        __syncthreads();
    }

    // epilogue: + bias, inverse shift-window scatter, float4 stores
    int winA = (m0 + wm * 64) >> 6;
    int b_img = winA / 144, wr = winA % 144;
    int wy = wr / 12, wx = wr % 12;
#pragma unroll
    for (int a = 0; a < 4; a++) {
        int n = n0 + wn * 64 + a * 16 + g4 * 4;
        float4 bv = *(const float4*)(bproj + n);
#pragma unroll
        for (int b = 0; b < 4; b++) {
            int t = b * 16 + l15;
            int yy = wy * 8 + (t >> 3) + 4; if (yy >= 96) yy -= 96;
            int xx = wx * 8 + (t & 7) + 4;  if (xx >= 96) xx -= 96;
            floatx4 o = acc[a][b];
            o[0] += bv.x; o[1] += bv.y; o[2] += bv.z; o[3] += bv.w;
            *(floatx4*)(&out[((size_t)b_img * 9216 + yy * 96 + xx) * 384 + n]) = o;
        }
    }
}

// ---------------- launcher ----------------
extern "C" void kernel_launch(void* const* d_in, const int* in_sizes, int n_in,
                              void* d_out, int out_size, void* d_ws, size_t ws_size,
                              hipStream_t stream) {
    const float* query = (const float*)d_in[0];
    const float* skipq = (const float*)d_in[1];
    const float* Wqkv  = (const float*)d_in[2];
    const float* bqkv  = (const float*)d_in[3];
    const float* Wskip = (const float*)d_in[4];
    const float* bskip = (const float*)d_in[5];
    const float* rpb   = (const float*)d_in[6];
    const float* Wproj = (const float*)d_in[7];
    const float* bproj = (const float*)d_in[8];
    float* out = (float*)d_out;

    int M = in_sizes[0] / 384;   // total tokens = 147456 for B=16
    int nwin = M / 64;           // 2304
    int mblocks = M / 128;       // 1152

    char* ws = (char*)d_ws;
    size_t off = 0;
    auto alloc = [&](size_t bytes) -> void* {
        void* p = ws + off;
        off = (off + bytes + 255) & ~(size_t)255;
        return p;
    };
    short* Wt     = (short*)alloc((size_t)1152 * 384 * 2);
    short* WtP    = (short*)alloc((size_t)384 * 384 * 2);
    float* bias64 = (float*)alloc((size_t)12 * 64 * 64 * 4);
    short* kbuf   = (short*)alloc((size_t)M * 384 * 2);
    short* vtbuf  = (short*)alloc((size_t)M * 384 * 2);
    short* qbuf   = (short*)alloc((size_t)M * 384 * 2);
    short* aout   = (short*)alloc((size_t)M * 384 * 2);
    (void)ws_size;

    hipLaunchKernelGGL(prep_wt, dim3(216), dim3(256), 0, stream, Wqkv, Wskip, Wt);
    hipLaunchKernelGGL(prep_wtp, dim3(72), dim3(256), 0, stream, Wproj, WtP);
    hipLaunchKernelGGL(prep_bias, dim3(192), dim3(256), 0, stream, rpb, bias64);
    hipLaunchKernelGGL(gemm_qkv, dim3(mblocks * 9), dim3(256), 0, stream,
                       query, skipq, Wt, bqkv, bskip, kbuf, vtbuf, qbuf);
    hipLaunchKernelGGL(attn_kernel, dim3(nwin * 12 / 4), dim3(256), 0, stream,
                       kbuf, vtbuf, qbuf, bias64, aout, nwin * 12);
    hipLaunchKernelGGL(gemm_proj, dim3(mblocks * 3), dim3(256), 0, stream,
                       aout, WtP, bproj, out);
}

// Round 6
// 587.765 us; speedup vs baseline: 1.0587x; 1.0587x over previous
//
#include <hip/hip_runtime.h>
#include <hip/hip_bf16.h>

// ShiftWindowMSA fused pipeline for MI355X (gfx950).
// R6: restructured GEMMs. Each block keeps a 128x384 A-slice resident in LDS
// and loops over all n-panels, streaming B via triple-buffered global_load_lds
// with counted s_waitcnt vmcnt(2) + raw s_barrier (never drain in-loop).
// gemm_qkv: grid (M/128, 2): var0 = query -> k,v panels 0..5; var1 = skip -> q 6..8.
// gemm_proj: same structure, 3 panels. attn unchanged.

typedef __attribute__((ext_vector_type(8))) short short8;
typedef __attribute__((ext_vector_type(4))) float floatx4;

#define MFMA16(a, b, c) __builtin_amdgcn_mfma_f32_16x16x32_bf16(a, b, c, 0, 0, 0)

__device__ __forceinline__ short f2bf(float f) {
    __hip_bfloat16 h = __float2bfloat16(f);
    return *reinterpret_cast<short*>(&h);
}

// packed fp32->bf16 RNE
__device__ __forceinline__ unsigned cvt2bf(float lo, float hi) {
    unsigned r;
    asm("v_cvt_pk_bf16_f32 %0, %1, %2" : "=v"(r) : "v"(lo), "v"(hi));
    return r;
}

__device__ __forceinline__ void glds16(const void* g, void* l) {
    __builtin_amdgcn_global_load_lds(
        (const __attribute__((address_space(1))) void*)g,
        (__attribute__((address_space(3))) void*)l, 16, 0, 0);
}

// ---------------- prep kernels ----------------

// Wt[1152][384] bf16: rows 0..767 = cols of W_qkv; 768.. = cols of W_skip * SCALE
__global__ __launch_bounds__(256) void prep_wt(const float* __restrict__ Wqkv,
                                               const float* __restrict__ Wskip,
                                               short* __restrict__ Wt) {
    int tid = blockIdx.x * 256 + threadIdx.x;  // 384*144 = 55296
    if (tid >= 384 * 144) return;
    int k = tid / 144;
    int n8 = (tid % 144) * 8;
#pragma unroll
    for (int e = 0; e < 8; e++) {
        int n = n8 + e;
        float v = (n < 768) ? Wqkv[k * 768 + n]
                            : Wskip[k * 384 + (n - 768)] * 0.17677669529663687f;
        Wt[(size_t)n * 384 + k] = f2bf(v);
    }
}

__global__ __launch_bounds__(256) void prep_wtp(const float* __restrict__ Wproj,
                                                short* __restrict__ WtP) {
    int tid = blockIdx.x * 256 + threadIdx.x;  // 384*48 = 18432
    if (tid >= 384 * 48) return;
    int k = tid / 48;
    int n8 = (tid % 48) * 8;
#pragma unroll
    for (int e = 0; e < 8; e++) {
        int n = n8 + e;
        WtP[(size_t)n * 384 + k] = f2bf(Wproj[k * 384 + n]);
    }
}

// bias64[h][i][kk] = rpb_table[r(i) + r(63-kk)][h],  r(t) = 15*(t>>3) + (t&7)
__global__ __launch_bounds__(256) void prep_bias(const float* __restrict__ rpb,
                                                 float* __restrict__ bias64) {
    int tid = blockIdx.x * 256 + threadIdx.x;  // 12*64*64 = 49152
    if (tid >= 49152) return;
    int h = tid >> 12;
    int rem = tid & 4095;
    int i = rem >> 6, kk = rem & 63;
    int j = 63 - kk;
    int ridx = 15 * (i >> 3) + (i & 7) + 15 * (j >> 3) + (j & 7);
    bias64[tid] = rpb[ridx * 12 + h];
}

// ---------------- gemm_qkv ----------------
__global__ __launch_bounds__(256) void gemm_qkv(
    const float* __restrict__ xq, const float* __restrict__ xs,
    const short* __restrict__ Wt,
    const float* __restrict__ bqkv, const float* __restrict__ bskip,
    short* __restrict__ kbuf, short* __restrict__ vtbuf, short* __restrict__ qbuf) {
    __shared__ short smem[61440];  // A[128][384] @0 (49152 sh); B: 3 halves x4096 @49152

    const int m0 = blockIdx.x * 128;
    const int var = blockIdx.y;          // 0: A=query, panels 0..5; 1: A=skip, panels 6..8
    const int nb0 = var ? 6 : 0;
    const int nbN = var ? 3 : 6;
    const float* __restrict__ src = var ? xs : xq;

    const int tid = threadIdx.x, lane = tid & 63, wid = tid >> 6;
    const int l15 = lane & 15, g4 = lane >> 4;
    const int wm = wid >> 1, wn = wid & 1;

    // ---- A gather: 128 rows x 384 fp32 (shift-window permuted) -> bf16 LDS ----
    {
        int r = tid >> 1, t2 = tid & 1;
        int g = m0 + r;
        int win = g >> 6, t = g & 63;
        int b = win / 144, wr = win % 144;
        int wy = wr / 12, wx = wr % 12;
        int yy = wy * 8 + (t >> 3) + 4; if (yy >= 96) yy -= 96;
        int xx = wx * 8 + (t & 7) + 4;  if (xx >= 96) xx -= 96;
        const float* rbase = src + ((size_t)b * 9216 + yy * 96 + xx) * 384;
        short* lrow = smem + r * 384;
        int r7 = r & 7;
#pragma unroll
        for (int j = 0; j < 24; j++) {
            int c = j * 2 + t2;
            float4 f0 = *(const float4*)(rbase + c * 8);
            float4 f1 = *(const float4*)(rbase + c * 8 + 4);
            uint4 u;
            u.x = cvt2bf(f0.x, f0.y); u.y = cvt2bf(f0.z, f0.w);
            u.z = cvt2bf(f1.x, f1.y); u.w = cvt2bf(f1.z, f1.w);
            *(uint4*)(lrow + ((c ^ r7) * 8)) = u;
        }
    }

    // ---- B staging roles (per wave: 2 glds of 1KB per step) ----
    int browoff[2], bdst[2];
#pragma unroll
    for (int j = 0; j < 2; j++) {
        int c0 = wid * 128 + j * 64;
        int c = c0 + lane;
        int brow = c >> 2, bs = c & 3;
        int sw = (brow ^ (brow >> 2)) & 3;
        browoff[j] = brow * 384 + (bs ^ sw) * 8;
        bdst[j] = 49152 + c0 * 8;
    }

    // fragment read offsets
    int arow[4];
#pragma unroll
    for (int mi = 0; mi < 4; mi++) arow[mi] = (wm * 64 + mi * 16 + l15) * 384;
    const int al7 = l15 & 7;
    const int xsw = (g4 ^ ((l15 ^ (l15 >> 2)) & 3)) * 8;
    int brof[4];
#pragma unroll
    for (int nj = 0; nj < 4; nj++) brof[nj] = 49152 + (wn * 64 + nj * 16 + l15) * 32 + xsw;

    // prologue: issue steps 0,1 of first panel, then full drain
    {
        const short* p0 = Wt + (size_t)nb0 * 49152;
#pragma unroll
        for (int j = 0; j < 2; j++) glds16(p0 + browoff[j], smem + bdst[j]);
#pragma unroll
        for (int j = 0; j < 2; j++) glds16(p0 + browoff[j] + 32, smem + bdst[j] + 4096);
    }
    __syncthreads();

    const short* bp = Wt + (size_t)nb0 * 49152;
    for (int pb = 0; pb < nbN; ++pb) {
        const int nb = nb0 + pb;
        const bool isv = (nb >= 3 && nb < 6);
        floatx4 acc[4][4];
#pragma unroll
        for (int a = 0; a < 4; a++)
#pragma unroll
            for (int b = 0; b < 4; b++)
#pragma unroll
                for (int r = 0; r < 4; r++) acc[a][b][r] = 0.f;

#pragma unroll
        for (int kt = 0; kt < 12; ++kt) {
            const int hR = kt % 3;
            const int choff = (((kt * 4 + g4) ^ al7)) * 8;
            short8 af[4], bfr[4];
#pragma unroll
            for (int mi = 0; mi < 4; mi++)
                af[mi] = *(const short8*)(smem + arow[mi] + choff);
#pragma unroll
            for (int nj = 0; nj < 4; nj++)
                bfr[nj] = *(const short8*)(smem + brof[nj] + hR * 4096);
            // prefetch step kt+2 (this or next panel)
            if (pb != nbN - 1 || kt < 10) {
                const short* ps = (kt < 10) ? bp : (bp + 49152);
                const int ko = (kt < 10) ? (kt + 2) * 32 : (kt - 10) * 32;
                const int hW = (kt + 2) % 3;
#pragma unroll
                for (int j = 0; j < 2; j++)
                    glds16(ps + browoff[j] + ko, smem + bdst[j] + hW * 4096);
            }
            if (isv) {
#pragma unroll
                for (int mi = 0; mi < 4; mi++)
#pragma unroll
                    for (int nj = 0; nj < 4; nj++)
                        acc[mi][nj] = MFMA16(af[mi], bfr[nj], acc[mi][nj]);
            } else {
#pragma unroll
                for (int a = 0; a < 4; a++)
#pragma unroll
                    for (int b = 0; b < 4; b++)
                        acc[a][b] = MFMA16(bfr[a], af[b], acc[a][b]);
            }
            asm volatile("s_waitcnt vmcnt(2)" ::: "memory");  // next step's pair landed
            __builtin_amdgcn_s_barrier();
        }

        // ---- epilogue for panel nb ----
        const int winA = (m0 + wm * 64) >> 6;
        const int ncol0 = nb * 128 + wn * 64;
        if (!isv) {
            short* buf;
            const float* bias;
            float scl;
            if (nb < 3) { buf = kbuf; bias = bqkv; scl = 1.0f; }
            else        { buf = qbuf; bias = bskip; scl = 0.17677669529663687f; }
#pragma unroll
            for (int a = 0; a < 4; a++) {
                int nbase = ncol0 + a * 16 + g4 * 4;
                int nm = (nb < 3) ? nbase : (nbase - 768);
                int head = nm >> 5, d0 = nm & 31;
                float4 bv = *(const float4*)(bias + nm);
                short* dst = buf + (size_t)(winA * 12 + head) * 2048 + d0;
#pragma unroll
                for (int b = 0; b < 4; b++) {
                    int t = b * 16 + l15;
                    uint2 pk;
                    pk.x = cvt2bf(acc[a][b][0] + bv.x * scl, acc[a][b][1] + bv.y * scl);
                    pk.y = cvt2bf(acc[a][b][2] + bv.z * scl, acc[a][b][3] + bv.w * scl);
                    *(uint2*)(dst + (size_t)t * 32) = pk;
                }
            }
        } else {
#pragma unroll
            for (int nj = 0; nj < 4; nj++) {
                int nm = ncol0 + nj * 16 + l15 - 384;
                int head = nm >> 5, d = nm & 31;
                float bvs = bqkv[384 + nm];
                short* dst = vtbuf + ((size_t)(winA * 12 + head) * 32 + d) * 64;
#pragma unroll
                for (int mi = 0; mi < 4; mi++) {
                    int t0 = mi * 16 + g4 * 4;
                    uint2 pk;
                    pk.x = cvt2bf(acc[mi][nj][0] + bvs, acc[mi][nj][1] + bvs);
                    pk.y = cvt2bf(acc[mi][nj][2] + bvs, acc[mi][nj][3] + bvs);
                    *(uint2*)(dst + t0) = pk;
                }
            }
        }
        asm volatile("s_waitcnt vmcnt(0)" ::: "memory");  // drain per panel: clean invariant
        bp += 49152;
    }
}

// ---------------- attention ----------------
__global__ __launch_bounds__(256) void attn_kernel(
    const short* __restrict__ kbuf, const short* __restrict__ vtbuf,
    const short* __restrict__ qbuf, const float* __restrict__ bias64,
    short* __restrict__ aout, int ntask) {
    __shared__ short lps[18432];  // 4 waves x 64 x 72
    int lane = threadIdx.x & 63, wid = threadIdx.x >> 6;
    int task = blockIdx.x * 4 + wid;
    if (task >= ntask) return;
    int win = task / 12, head = task % 12;
    int l15 = lane & 15, g4 = lane >> 4;

    const short* kb = kbuf + (size_t)task * 2048;
    const short* qb = qbuf + (size_t)task * 2048;
    const short* vb = vtbuf + (size_t)task * 2048;

    short8 kf[4], qf[4], vf[2][2];
#pragma unroll
    for (int mi = 0; mi < 4; mi++)
        kf[mi] = *(const short8*)(kb + (mi * 16 + l15) * 32 + g4 * 8);
#pragma unroll
    for (int nj = 0; nj < 4; nj++)
        qf[nj] = *(const short8*)(qb + (nj * 16 + l15) * 32 + g4 * 8);
#pragma unroll
    for (int ma = 0; ma < 2; ma++)
#pragma unroll
        for (int ks = 0; ks < 2; ks++)
            vf[ma][ks] = *(const short8*)(vb + (ma * 16 + l15) * 64 + ks * 32 + g4 * 8);

    floatx4 st[4][4];
#pragma unroll
    for (int mi = 0; mi < 4; mi++)
#pragma unroll
        for (int nj = 0; nj < 4; nj++)
#pragma unroll
            for (int r = 0; r < 4; r++) st[mi][nj][r] = 0.f;

#pragma unroll
    for (int mi = 0; mi < 4; mi++)
#pragma unroll
        for (int nj = 0; nj < 4; nj++)
            st[mi][nj] = MFMA16(kf[mi], qf[nj], st[mi][nj]);  // S^T[kk][i]

    const float* bb = bias64 + head * 4096;
#pragma unroll
    for (int nj = 0; nj < 4; nj++) {
        int i = nj * 16 + l15;
#pragma unroll
        for (int mi = 0; mi < 4; mi++) {
            floatx4 b4 = *(const floatx4*)(bb + i * 64 + mi * 16 + g4 * 4);
            st[mi][nj] += b4;
        }
    }

    int wr = win % 144;
    int wy = wr / 12, wx = wr % 12;
    if (wy == 11 || wx == 11) {
        int wy11 = (wy == 11), wx11 = (wx == 11);
        int ri[4];
#pragma unroll
        for (int nj = 0; nj < 4; nj++) {
            int t = nj * 16 + l15;
            int hh = wy11 ? (((t >> 3) >= 4) ? 2 : 1) : 0;
            int ww = wx11 ? (((t & 7) >= 4) ? 2 : 1) : 0;
            ri[nj] = hh * 3 + ww;
        }
#pragma unroll
        for (int mi = 0; mi < 4; mi++)
#pragma unroll
            for (int r = 0; r < 4; r++) {
                int t = mi * 16 + g4 * 4 + r;
                int hh = wy11 ? (((t >> 3) >= 4) ? 2 : 1) : 0;
                int ww = wx11 ? (((t & 7) >= 4) ? 2 : 1) : 0;
                int rk = hh * 3 + ww;
#pragma unroll
                for (int nj = 0; nj < 4; nj++)
                    if (rk != ri[nj]) st[mi][nj][r] -= 100.0f;
            }
    }

    float rden[4];
#pragma unroll
    for (int nj = 0; nj < 4; nj++) {
        float m = -1e30f;
#pragma unroll
        for (int mi = 0; mi < 4; mi++)
#pragma unroll
            for (int r = 0; r < 4; r++) m = fmaxf(m, st[mi][nj][r]);
        m = fmaxf(m, __shfl_xor(m, 16));
        m = fmaxf(m, __shfl_xor(m, 32));
        float s = 0.f;
#pragma unroll
        for (int mi = 0; mi < 4; mi++)
#pragma unroll
            for (int r = 0; r < 4; r++) {
                float p = __expf(st[mi][nj][r] - m);
                st[mi][nj][r] = p;
                s += p;
            }
        s += __shfl_xor(s, 16);
        s += __shfl_xor(s, 32);
        rden[nj] = 1.0f / s;
    }

    short* Lp = lps + wid * 4608;  // [64][72]
#pragma unroll
    for (int mi = 0; mi < 4; mi++)
#pragma unroll
        for (int nj = 0; nj < 4; nj++) {
            uint2 pk;
            pk.x = cvt2bf(st[mi][nj][0], st[mi][nj][1]);
            pk.y = cvt2bf(st[mi][nj][2], st[mi][nj][3]);
            *(uint2*)(Lp + (nj * 16 + l15) * 72 + mi * 16 + g4 * 4) = pk;
        }

    floatx4 o[2][4];
#pragma unroll
    for (int ma = 0; ma < 2; ma++)
#pragma unroll
        for (int nj = 0; nj < 4; nj++)
#pragma unroll
            for (int r = 0; r < 4; r++) o[ma][nj][r] = 0.f;
#pragma unroll
    for (int ks = 0; ks < 2; ks++) {
        short8 pb[4];
#pragma unroll
        for (int nj = 0; nj < 4; nj++)
            pb[nj] = *(const short8*)(Lp + (nj * 16 + l15) * 72 + ks * 32 + g4 * 8);
#pragma unroll
        for (int ma = 0; ma < 2; ma++)
#pragma unroll
            for (int nj = 0; nj < 4; nj++)
                o[ma][nj] = MFMA16(vf[ma][ks], pb[nj], o[ma][nj]);
    }

    short* ob = aout + (size_t)win * 64 * 384 + head * 32;
#pragma unroll
    for (int ma = 0; ma < 2; ma++)
#pragma unroll
        for (int nj = 0; nj < 4; nj++) {
            int i = nj * 16 + l15;
            uint2 pk;
            pk.x = cvt2bf(o[ma][nj][0] * rden[nj], o[ma][nj][1] * rden[nj]);
            pk.y = cvt2bf(o[ma][nj][2] * rden[nj], o[ma][nj][3] * rden[nj]);
            *(uint2*)(ob + (size_t)i * 384 + ma * 16 + g4 * 4) = pk;
        }
}

// ---------------- gemm_proj ----------------
__global__ __launch_bounds__(256) void gemm_proj(
    const short* __restrict__ aout, const short* __restrict__ WtP,
    const float* __restrict__ bproj, float* __restrict__ out) {
    __shared__ short smem[61440];  // A[128][384] @0; B: 3 halves x4096 @49152

    const int m0 = blockIdx.x * 128;
    const int tid = threadIdx.x, lane = tid & 63, wid = tid >> 6;
    const int l15 = lane & 15, g4 = lane >> 4;
    const int wm = wid >> 1, wn = wid & 1;

    // ---- A via glds: 96 issues of 1KB, pre-swizzled source chunks ----
#pragma unroll
    for (int j = 0; j < 24; j++) {
        int i = wid * 24 + j;
        int c = i * 64 + lane;
        int row = c / 48, ch = c - row * 48;
        const short* s = aout + (size_t)(m0 + row) * 384 + ((ch ^ (row & 7)) * 8);
        glds16(s, smem + i * 512);
    }

    int browoff[2], bdst[2];
#pragma unroll
    for (int j = 0; j < 2; j++) {
        int c0 = wid * 128 + j * 64;
        int c = c0 + lane;
        int brow = c >> 2, bs = c & 3;
        int sw = (brow ^ (brow >> 2)) & 3;
        browoff[j] = brow * 384 + (bs ^ sw) * 8;
        bdst[j] = 49152 + c0 * 8;
    }

    int arow[4];
#pragma unroll
    for (int mi = 0; mi < 4; mi++) arow[mi] = (wm * 64 + mi * 16 + l15) * 384;
    const int al7 = l15 & 7;
    const int xsw = (g4 ^ ((l15 ^ (l15 >> 2)) & 3)) * 8;
    int brof[4];
#pragma unroll
    for (int nj = 0; nj < 4; nj++) brof[nj] = 49152 + (wn * 64 + nj * 16 + l15) * 32 + xsw;

    {
#pragma unroll
        for (int j = 0; j < 2; j++) glds16(WtP + browoff[j], smem + bdst[j]);
#pragma unroll
        for (int j = 0; j < 2; j++) glds16(WtP + browoff[j] + 32, smem + bdst[j] + 4096);
    }
    __syncthreads();

    const int winA = (m0 + wm * 64) >> 6;
    const int b_img = winA / 144, wrw = winA % 144;
    const int wy = wrw / 12, wx = wrw % 12;

    const short* bp = WtP;
    for (int pb = 0; pb < 3; ++pb) {
        floatx4 acc[4][4];
#pragma unroll
        for (int a = 0; a < 4; a++)
#pragma unroll
            for (int b = 0; b < 4; b++)
#pragma unroll
                for (int r = 0; r < 4; r++) acc[a][b][r] = 0.f;

#pragma unroll
        for (int kt = 0; kt < 12; ++kt) {
            const int hR = kt % 3;
            const int choff = (((kt * 4 + g4) ^ al7)) * 8;
            short8 af[4], bfr[4];
#pragma unroll
            for (int mi = 0; mi < 4; mi++)
                af[mi] = *(const short8*)(smem + arow[mi] + choff);
#pragma unroll
            for (int nj = 0; nj < 4; nj++)
                bfr[nj] = *(const short8*)(smem + brof[nj] + hR * 4096);
            if (pb != 2 || kt < 10) {
                const short* ps = (kt < 10) ? bp : (bp + 49152);
                const int ko = (kt < 10) ? (kt + 2) * 32 : (kt - 10) * 32;
                const int hW = (kt + 2) % 3;
#pragma unroll
                for (int j = 0; j < 2; j++)
                    glds16(ps + browoff[j] + ko, smem + bdst[j] + hW * 4096);
            }
#pragma unroll
            for (int a = 0; a < 4; a++)
#pragma unroll
                for (int b = 0; b < 4; b++)
                    acc[a][b] = MFMA16(bfr[a], af[b], acc[a][b]);
            asm volatile("s_waitcnt vmcnt(2)" ::: "memory");
            __builtin_amdgcn_s_barrier();
        }

        // epilogue: + bias, inverse shift-window scatter, float4 stores
#pragma unroll
        for (int a = 0; a < 4; a++) {
            int n = pb * 128 + wn * 64 + a * 16 + g4 * 4;
            float4 bv = *(const float4*)(bproj + n);
#pragma unroll
            for (int b = 0; b < 4; b++) {
                int t = b * 16 + l15;
                int yy = wy * 8 + (t >> 3) + 4; if (yy >= 96) yy -= 96;
                int xx = wx * 8 + (t & 7) + 4;  if (xx >= 96) xx -= 96;
                floatx4 o = acc[a][b];
                o[0] += bv.x; o[1] += bv.y; o[2] += bv.z; o[3] += bv.w;
                *(floatx4*)(&out[((size_t)b_img * 9216 + yy * 96 + xx) * 384 + n]) = o;
            }
        }
        asm volatile("s_waitcnt vmcnt(0)" ::: "memory");
        bp += 49152;
    }
}

// ---------------- launcher ----------------
extern "C" void kernel_launch(void* const* d_in, const int* in_sizes, int n_in,
                              void* d_out, int out_size, void* d_ws, size_t ws_size,
                              hipStream_t stream) {
    const float* query = (const float*)d_in[0];
    const float* skipq = (const float*)d_in[1];
    const float* Wqkv  = (const float*)d_in[2];
    const float* bqkv  = (const float*)d_in[3];
    const float* Wskip = (const float*)d_in[4];
    const float* bskip = (const float*)d_in[5];
    const float* rpb   = (const float*)d_in[6];
    const float* Wproj = (const float*)d_in[7];
    const float* bproj = (const float*)d_in[8];
    float* out = (float*)d_out;

    int M = in_sizes[0] / 384;   // total tokens = 147456 for B=16
    int nwin = M / 64;           // 2304
    int mblocks = M / 128;       // 1152

    char* ws = (char*)d_ws;
    size_t off = 0;
    auto alloc = [&](size_t bytes) -> void* {
        void* p = ws + off;
        off = (off + bytes + 255) & ~(size_t)255;
        return p;
    };
    short* Wt     = (short*)alloc((size_t)1152 * 384 * 2);
    short* WtP    = (short*)alloc((size_t)384 * 384 * 2);
    float* bias64 = (float*)alloc((size_t)12 * 64 * 64 * 4);
    short* kbuf   = (short*)alloc((size_t)M * 384 * 2);
    short* vtbuf  = (short*)alloc((size_t)M * 384 * 2);
    short* qbuf   = (short*)alloc((size_t)M * 384 * 2);
    short* aout   = (short*)alloc((size_t)M * 384 * 2);
    (void)ws_size;

    hipLaunchKernelGGL(prep_wt, dim3(216), dim3(256), 0, stream, Wqkv, Wskip, Wt);
    hipLaunchKernelGGL(prep_wtp, dim3(72), dim3(256), 0, stream, Wproj, WtP);
    hipLaunchKernelGGL(prep_bias, dim3(192), dim3(256), 0, stream, rpb, bias64);
    hipLaunchKernelGGL(gemm_qkv, dim3(mblocks, 2), dim3(256), 0, stream,
                       query, skipq, Wt, bqkv, bskip, kbuf, vtbuf, qbuf);
    hipLaunchKernelGGL(attn_kernel, dim3(nwin * 12 / 4), dim3(256), 0, stream,
                       kbuf, vtbuf, qbuf, bias64, aout, nwin * 12);
    hipLaunchKernelGGL(gemm_proj, dim3(mblocks), dim3(256), 0, stream,
                       aout, WtP, bproj, out);
}

// Round 7
// 533.993 us; speedup vs baseline: 1.1654x; 1.1007x over previous
//
#include <hip/hip_runtime.h>
#include <hip/hip_bf16.h>

// ShiftWindowMSA fused pipeline for MI355X (gfx950).
// R7: BM=64 (one window per block), 72 KB LDS -> 2 blocks/CU (8 waves/CU).
// A-slice resident in LDS; B streamed via triple-buffered global_load_lds with
// counted s_waitcnt vmcnt(2) + raw s_barrier (vmcnt(0) once at last-panel kt=10).
// gemm_qkv grid (nwin, 2): var0 = query -> k,v panels 0..5; var1 = skip -> q 6..8.
// gemm_proj same structure, 3 panels. attn unchanged.

typedef __attribute__((ext_vector_type(8))) short short8;
typedef __attribute__((ext_vector_type(4))) float floatx4;

#define MFMA16(a, b, c) __builtin_amdgcn_mfma_f32_16x16x32_bf16(a, b, c, 0, 0, 0)

__device__ __forceinline__ short f2bf(float f) {
    __hip_bfloat16 h = __float2bfloat16(f);
    return *reinterpret_cast<short*>(&h);
}

// packed fp32->bf16 RNE
__device__ __forceinline__ unsigned cvt2bf(float lo, float hi) {
    unsigned r;
    asm("v_cvt_pk_bf16_f32 %0, %1, %2" : "=v"(r) : "v"(lo), "v"(hi));
    return r;
}

__device__ __forceinline__ void glds16(const void* g, void* l) {
    __builtin_amdgcn_global_load_lds(
        (const __attribute__((address_space(1))) void*)g,
        (__attribute__((address_space(3))) void*)l, 16, 0, 0);
}

// ---------------- prep kernels ----------------

// Wt[1152][384] bf16: rows 0..767 = cols of W_qkv; 768.. = cols of W_skip * SCALE
__global__ __launch_bounds__(256) void prep_wt(const float* __restrict__ Wqkv,
                                               const float* __restrict__ Wskip,
                                               short* __restrict__ Wt) {
    int tid = blockIdx.x * 256 + threadIdx.x;  // 384*144 = 55296
    if (tid >= 384 * 144) return;
    int k = tid / 144;
    int n8 = (tid % 144) * 8;
#pragma unroll
    for (int e = 0; e < 8; e++) {
        int n = n8 + e;
        float v = (n < 768) ? Wqkv[k * 768 + n]
                            : Wskip[k * 384 + (n - 768)] * 0.17677669529663687f;
        Wt[(size_t)n * 384 + k] = f2bf(v);
    }
}

__global__ __launch_bounds__(256) void prep_wtp(const float* __restrict__ Wproj,
                                                short* __restrict__ WtP) {
    int tid = blockIdx.x * 256 + threadIdx.x;  // 384*48 = 18432
    if (tid >= 384 * 48) return;
    int k = tid / 48;
    int n8 = (tid % 48) * 8;
#pragma unroll
    for (int e = 0; e < 8; e++) {
        int n = n8 + e;
        WtP[(size_t)n * 384 + k] = f2bf(Wproj[k * 384 + n]);
    }
}

// bias64[h][i][kk] = rpb_table[r(i) + r(63-kk)][h],  r(t) = 15*(t>>3) + (t&7)
__global__ __launch_bounds__(256) void prep_bias(const float* __restrict__ rpb,
                                                 float* __restrict__ bias64) {
    int tid = blockIdx.x * 256 + threadIdx.x;  // 12*64*64 = 49152
    if (tid >= 49152) return;
    int h = tid >> 12;
    int rem = tid & 4095;
    int i = rem >> 6, kk = rem & 63;
    int j = 63 - kk;
    int ridx = 15 * (i >> 3) + (i & 7) + 15 * (j >> 3) + (j & 7);
    bias64[tid] = rpb[ridx * 12 + h];
}

// ---------------- gemm_qkv ----------------
// LDS: A[64][384] bf16 @0 (24576 sh = 48 KB); B: 3 bufs x 4096 sh @24576 (24 KB).
__global__ __launch_bounds__(256) void gemm_qkv(
    const float* __restrict__ xq, const float* __restrict__ xs,
    const short* __restrict__ Wt,
    const float* __restrict__ bqkv, const float* __restrict__ bskip,
    short* __restrict__ kbuf, short* __restrict__ vtbuf, short* __restrict__ qbuf) {
    __shared__ short smem[36864];  // 73728 B -> 2 blocks/CU
    const int ABASE = 24576;

    const int win = blockIdx.x;          // one window per block
    const int var = blockIdx.y;          // 0: A=query, panels 0..5; 1: A=skip, 6..8
    const int nb0 = var ? 6 : 0;
    const int nbN = var ? 3 : 6;
    const float* __restrict__ src = var ? xs : xq;

    const int tid = threadIdx.x, lane = tid & 63, wid = tid >> 6;
    const int l15 = lane & 15, g4 = lane >> 4;
    const int wm = wid >> 1, wn = wid & 1;   // wave tile 32 x 64

    // ---- A gather: 64 rows (window tokens) x 384 fp32 -> bf16 LDS, swizzled ----
    {
        int r = tid >> 2, q4 = tid & 3;
        int b = win / 144, wr = win % 144;
        int wy = wr / 12, wx = wr % 12;
        int yy = wy * 8 + (r >> 3) + 4; if (yy >= 96) yy -= 96;
        int xx = wx * 8 + (r & 7) + 4;  if (xx >= 96) xx -= 96;
        const float* rbase = src + ((size_t)b * 9216 + yy * 96 + xx) * 384;
        short* lrow = smem + r * 384;
        int r7 = r & 7;
#pragma unroll
        for (int j = 0; j < 12; j++) {
            int c = q4 + j * 4;
            float4 f0 = *(const float4*)(rbase + c * 8);
            float4 f1 = *(const float4*)(rbase + c * 8 + 4);
            uint4 u;
            u.x = cvt2bf(f0.x, f0.y); u.y = cvt2bf(f0.z, f0.w);
            u.z = cvt2bf(f1.x, f1.y); u.w = cvt2bf(f1.z, f1.w);
            *(uint4*)(lrow + ((c ^ r7) * 8)) = u;
        }
    }

    // ---- B staging roles (8 glds of 1KB per step; 2 per wave) ----
    int browoff[2], bdst[2];
#pragma unroll
    for (int j = 0; j < 2; j++) {
        int c0 = wid * 128 + j * 64;
        int c = c0 + lane;
        int brow = c >> 2, bs = c & 3;
        int sw = (brow ^ (brow >> 2)) & 3;
        browoff[j] = brow * 384 + (bs ^ sw) * 8;
        bdst[j] = ABASE + c0 * 8;
    }

    // fragment read offsets
    int arow[2];
#pragma unroll
    for (int b = 0; b < 2; b++) arow[b] = (wm * 32 + b * 16 + l15) * 384;
    const int al7 = l15 & 7;
    const int xsw = (g4 ^ ((l15 ^ (l15 >> 2)) & 3)) * 8;
    int brof[4];
#pragma unroll
    for (int nj = 0; nj < 4; nj++) brof[nj] = ABASE + (wn * 64 + nj * 16 + l15) * 32 + xsw;

    // prologue: issue steps 0,1 of first panel, then full drain
    {
        const short* p0 = Wt + (size_t)nb0 * 49152;
#pragma unroll
        for (int j = 0; j < 2; j++) glds16(p0 + browoff[j], smem + bdst[j]);
#pragma unroll
        for (int j = 0; j < 2; j++) glds16(p0 + browoff[j] + 32, smem + bdst[j] + 4096);
    }
    __syncthreads();

    const short* bp = Wt + (size_t)nb0 * 49152;
    for (int pb = 0; pb < nbN; ++pb) {
        const int nb = nb0 + pb;
        const bool isv = (nb >= 3 && nb < 6);
        const bool lastp = (pb == nbN - 1);
        floatx4 acc[4][2];  // swapped: [nfrag][tfrag]; v uses [tfrag][nfrag] view below
        floatx4 accv[2][4];
#pragma unroll
        for (int a = 0; a < 4; a++)
#pragma unroll
            for (int b = 0; b < 2; b++)
#pragma unroll
                for (int r = 0; r < 4; r++) { acc[a][b][r] = 0.f; }
#pragma unroll
        for (int a = 0; a < 2; a++)
#pragma unroll
            for (int b = 0; b < 4; b++)
#pragma unroll
                for (int r = 0; r < 4; r++) { accv[a][b][r] = 0.f; }

#pragma unroll
        for (int kt = 0; kt < 12; ++kt) {
            const int hR = kt % 3;
            const int choff = ((kt * 4 + g4) ^ al7) * 8;
            short8 af[2], bfr[4];
#pragma unroll
            for (int b = 0; b < 2; b++)
                af[b] = *(const short8*)(smem + arow[b] + choff);
#pragma unroll
            for (int nj = 0; nj < 4; nj++)
                bfr[nj] = *(const short8*)(smem + brof[nj] + hR * 4096);
            // prefetch step kt+2 (this or next panel)
            if (!lastp || kt < 10) {
                const short* ps = (kt < 10) ? bp : (bp + 49152);
                const int ko = (kt < 10) ? (kt + 2) * 32 : (kt - 10) * 32;
                const int hW = (kt + 2) % 3;
#pragma unroll
                for (int j = 0; j < 2; j++)
                    glds16(ps + browoff[j] + ko, smem + bdst[j] + hW * 4096);
            }
            if (isv) {
#pragma unroll
                for (int a = 0; a < 2; a++)
#pragma unroll
                    for (int b = 0; b < 4; b++)
                        accv[a][b] = MFMA16(af[a], bfr[b], accv[a][b]);
            } else {
#pragma unroll
                for (int a = 0; a < 4; a++)
#pragma unroll
                    for (int b = 0; b < 2; b++)
                        acc[a][b] = MFMA16(bfr[a], af[b], acc[a][b]);
            }
            if (lastp && kt == 10) {
                asm volatile("s_waitcnt vmcnt(0)" ::: "memory");
            } else {
                asm volatile("s_waitcnt vmcnt(2)" ::: "memory");
            }
            __builtin_amdgcn_s_barrier();
        }

        // ---- epilogue for panel nb ----
        const int ncol0 = nb * 128 + wn * 64;
        if (!isv) {
            short* buf;
            const float* bias;
            float scl;
            if (nb < 3) { buf = kbuf; bias = bqkv; scl = 1.0f; }
            else        { buf = qbuf; bias = bskip; scl = 0.17677669529663687f; }
#pragma unroll
            for (int a = 0; a < 4; a++) {
                int nbase = ncol0 + a * 16 + g4 * 4;
                int nm = (nb < 3) ? nbase : (nbase - 768);
                int head = nm >> 5, d0 = nm & 31;
                float4 bv = *(const float4*)(bias + nm);
                short* dst = buf + (size_t)(win * 12 + head) * 2048 + d0;
#pragma unroll
                for (int b = 0; b < 2; b++) {
                    int t = wm * 32 + b * 16 + l15;
                    uint2 pk;
                    pk.x = cvt2bf(acc[a][b][0] + bv.x * scl, acc[a][b][1] + bv.y * scl);
                    pk.y = cvt2bf(acc[a][b][2] + bv.z * scl, acc[a][b][3] + bv.w * scl);
                    *(uint2*)(dst + (size_t)t * 32) = pk;
                }
            }
        } else {
#pragma unroll
            for (int nj = 0; nj < 4; nj++) {
                int nm = ncol0 + nj * 16 + l15 - 384;
                int head = nm >> 5, d = nm & 31;
                float bvs = bqkv[384 + nm];
                short* dst = vtbuf + ((size_t)(win * 12 + head) * 32 + d) * 64;
#pragma unroll
                for (int mi = 0; mi < 2; mi++) {
                    int t0 = wm * 32 + mi * 16 + g4 * 4;
                    uint2 pk;
                    pk.x = cvt2bf(accv[mi][nj][0] + bvs, accv[mi][nj][1] + bvs);
                    pk.y = cvt2bf(accv[mi][nj][2] + bvs, accv[mi][nj][3] + bvs);
                    *(uint2*)(dst + t0) = pk;
                }
            }
        }
        bp += 49152;
    }
}

// ---------------- attention ----------------
__global__ __launch_bounds__(256) void attn_kernel(
    const short* __restrict__ kbuf, const short* __restrict__ vtbuf,
    const short* __restrict__ qbuf, const float* __restrict__ bias64,
    short* __restrict__ aout, int ntask) {
    __shared__ short lps[18432];  // 4 waves x 64 x 72
    int lane = threadIdx.x & 63, wid = threadIdx.x >> 6;
    int task = blockIdx.x * 4 + wid;
    if (task >= ntask) return;
    int win = task / 12, head = task % 12;
    int l15 = lane & 15, g4 = lane >> 4;

    const short* kb = kbuf + (size_t)task * 2048;
    const short* qb = qbuf + (size_t)task * 2048;
    const short* vb = vtbuf + (size_t)task * 2048;

    short8 kf[4], qf[4], vf[2][2];
#pragma unroll
    for (int mi = 0; mi < 4; mi++)
        kf[mi] = *(const short8*)(kb + (mi * 16 + l15) * 32 + g4 * 8);
#pragma unroll
    for (int nj = 0; nj < 4; nj++)
        qf[nj] = *(const short8*)(qb + (nj * 16 + l15) * 32 + g4 * 8);
#pragma unroll
    for (int ma = 0; ma < 2; ma++)
#pragma unroll
        for (int ks = 0; ks < 2; ks++)
            vf[ma][ks] = *(const short8*)(vb + (ma * 16 + l15) * 64 + ks * 32 + g4 * 8);

    floatx4 st[4][4];
#pragma unroll
    for (int mi = 0; mi < 4; mi++)
#pragma unroll
        for (int nj = 0; nj < 4; nj++)
#pragma unroll
            for (int r = 0; r < 4; r++) st[mi][nj][r] = 0.f;

#pragma unroll
    for (int mi = 0; mi < 4; mi++)
#pragma unroll
        for (int nj = 0; nj < 4; nj++)
            st[mi][nj] = MFMA16(kf[mi], qf[nj], st[mi][nj]);  // S^T[kk][i]

    const float* bb = bias64 + head * 4096;
#pragma unroll
    for (int nj = 0; nj < 4; nj++) {
        int i = nj * 16 + l15;
#pragma unroll
        for (int mi = 0; mi < 4; mi++) {
            floatx4 b4 = *(const floatx4*)(bb + i * 64 + mi * 16 + g4 * 4);
            st[mi][nj] += b4;
        }
    }

    int wr = win % 144;
    int wy = wr / 12, wx = wr % 12;
    if (wy == 11 || wx == 11) {
        int wy11 = (wy == 11), wx11 = (wx == 11);
        int ri[4];
#pragma unroll
        for (int nj = 0; nj < 4; nj++) {
            int t = nj * 16 + l15;
            int hh = wy11 ? (((t >> 3) >= 4) ? 2 : 1) : 0;
            int ww = wx11 ? (((t & 7) >= 4) ? 2 : 1) : 0;
            ri[nj] = hh * 3 + ww;
        }
#pragma unroll
        for (int mi = 0; mi < 4; mi++)
#pragma unroll
            for (int r = 0; r < 4; r++) {
                int t = mi * 16 + g4 * 4 + r;
                int hh = wy11 ? (((t >> 3) >= 4) ? 2 : 1) : 0;
                int ww = wx11 ? (((t & 7) >= 4) ? 2 : 1) : 0;
                int rk = hh * 3 + ww;
#pragma unroll
                for (int nj = 0; nj < 4; nj++)
                    if (rk != ri[nj]) st[mi][nj][r] -= 100.0f;
            }
    }

    float rden[4];
#pragma unroll
    for (int nj = 0; nj < 4; nj++) {
        float m = -1e30f;
#pragma unroll
        for (int mi = 0; mi < 4; mi++)
#pragma unroll
            for (int r = 0; r < 4; r++) m = fmaxf(m, st[mi][nj][r]);
        m = fmaxf(m, __shfl_xor(m, 16));
        m = fmaxf(m, __shfl_xor(m, 32));
        float s = 0.f;
#pragma unroll
        for (int mi = 0; mi < 4; mi++)
#pragma unroll
            for (int r = 0; r < 4; r++) {
                float p = __expf(st[mi][nj][r] - m);
                st[mi][nj][r] = p;
                s += p;
            }
        s += __shfl_xor(s, 16);
        s += __shfl_xor(s, 32);
        rden[nj] = 1.0f / s;
    }

    short* Lp = lps + wid * 4608;  // [64][72]
#pragma unroll
    for (int mi = 0; mi < 4; mi++)
#pragma unroll
        for (int nj = 0; nj < 4; nj++) {
            uint2 pk;
            pk.x = cvt2bf(st[mi][nj][0], st[mi][nj][1]);
            pk.y = cvt2bf(st[mi][nj][2], st[mi][nj][3]);
            *(uint2*)(Lp + (nj * 16 + l15) * 72 + mi * 16 + g4 * 4) = pk;
        }

    floatx4 o[2][4];
#pragma unroll
    for (int ma = 0; ma < 2; ma++)
#pragma unroll
        for (int nj = 0; nj < 4; nj++)
#pragma unroll
            for (int r = 0; r < 4; r++) o[ma][nj][r] = 0.f;
#pragma unroll
    for (int ks = 0; ks < 2; ks++) {
        short8 pb[4];
#pragma unroll
        for (int nj = 0; nj < 4; nj++)
            pb[nj] = *(const short8*)(Lp + (nj * 16 + l15) * 72 + ks * 32 + g4 * 8);
#pragma unroll
        for (int ma = 0; ma < 2; ma++)
#pragma unroll
            for (int nj = 0; nj < 4; nj++)
                o[ma][nj] = MFMA16(vf[ma][ks], pb[nj], o[ma][nj]);
    }

    short* ob = aout + (size_t)win * 64 * 384 + head * 32;
#pragma unroll
    for (int ma = 0; ma < 2; ma++)
#pragma unroll
        for (int nj = 0; nj < 4; nj++) {
            int i = nj * 16 + l15;
            uint2 pk;
            pk.x = cvt2bf(o[ma][nj][0] * rden[nj], o[ma][nj][1] * rden[nj]);
            pk.y = cvt2bf(o[ma][nj][2] * rden[nj], o[ma][nj][3] * rden[nj]);
            *(uint2*)(ob + (size_t)i * 384 + ma * 16 + g4 * 4) = pk;
        }
}

// ---------------- gemm_proj ----------------
// Same structure; A (bf16) staged via glds with pre-swizzled source chunks.
__global__ __launch_bounds__(256) void gemm_proj(
    const short* __restrict__ aout, const short* __restrict__ WtP,
    const float* __restrict__ bproj, float* __restrict__ out) {
    __shared__ short smem[36864];
    const int ABASE = 24576;

    const int win = blockIdx.x;
    const int m0 = win * 64;
    const int tid = threadIdx.x, lane = tid & 63, wid = tid >> 6;
    const int l15 = lane & 15, g4 = lane >> 4;
    const int wm = wid >> 1, wn = wid & 1;

    // ---- A via glds: 48 issues of 1KB (12 per wave) ----
#pragma unroll
    for (int j = 0; j < 12; j++) {
        int i = wid * 12 + j;
        int c = i * 64 + lane;
        int row = c / 48, ch = c - row * 48;
        const short* s = aout + (size_t)(m0 + row) * 384 + ((ch ^ (row & 7)) * 8);
        glds16(s, smem + i * 512);
    }

    int browoff[2], bdst[2];
#pragma unroll
    for (int j = 0; j < 2; j++) {
        int c0 = wid * 128 + j * 64;
        int c = c0 + lane;
        int brow = c >> 2, bs = c & 3;
        int sw = (brow ^ (brow >> 2)) & 3;
        browoff[j] = brow * 384 + (bs ^ sw) * 8;
        bdst[j] = ABASE + c0 * 8;
    }

    int arow[2];
#pragma unroll
    for (int b = 0; b < 2; b++) arow[b] = (wm * 32 + b * 16 + l15) * 384;
    const int al7 = l15 & 7;
    const int xsw = (g4 ^ ((l15 ^ (l15 >> 2)) & 3)) * 8;
    int brof[4];
#pragma unroll
    for (int nj = 0; nj < 4; nj++) brof[nj] = ABASE + (wn * 64 + nj * 16 + l15) * 32 + xsw;

    {
#pragma unroll
        for (int j = 0; j < 2; j++) glds16(WtP + browoff[j], smem + bdst[j]);
#pragma unroll
        for (int j = 0; j < 2; j++) glds16(WtP + browoff[j] + 32, smem + bdst[j] + 4096);
    }
    __syncthreads();

    const int b_img = win / 144, wrw = win % 144;
    const int wy = wrw / 12, wx = wrw % 12;

    const short* bp = WtP;
    for (int pb = 0; pb < 3; ++pb) {
        const bool lastp = (pb == 2);
        floatx4 acc[4][2];
#pragma unroll
        for (int a = 0; a < 4; a++)
#pragma unroll
            for (int b = 0; b < 2; b++)
#pragma unroll
                for (int r = 0; r < 4; r++) acc[a][b][r] = 0.f;

#pragma unroll
        for (int kt = 0; kt < 12; ++kt) {
            const int hR = kt % 3;
            const int choff = ((kt * 4 + g4) ^ al7) * 8;
            short8 af[2], bfr[4];
#pragma unroll
            for (int b = 0; b < 2; b++)
                af[b] = *(const short8*)(smem + arow[b] + choff);
#pragma unroll
            for (int nj = 0; nj < 4; nj++)
                bfr[nj] = *(const short8*)(smem + brof[nj] + hR * 4096);
            if (!lastp || kt < 10) {
                const short* ps = (kt < 10) ? bp : (bp + 49152);
                const int ko = (kt < 10) ? (kt + 2) * 32 : (kt - 10) * 32;
                const int hW = (kt + 2) % 3;
#pragma unroll
                for (int j = 0; j < 2; j++)
                    glds16(ps + browoff[j] + ko, smem + bdst[j] + hW * 4096);
            }
#pragma unroll
            for (int a = 0; a < 4; a++)
#pragma unroll
                for (int b = 0; b < 2; b++)
                    acc[a][b] = MFMA16(bfr[a], af[b], acc[a][b]);
            if (lastp && kt == 10) {
                asm volatile("s_waitcnt vmcnt(0)" ::: "memory");
            } else {
                asm volatile("s_waitcnt vmcnt(2)" ::: "memory");
            }
            __builtin_amdgcn_s_barrier();
        }

        // epilogue: + bias, inverse shift-window scatter, float4 stores
#pragma unroll
        for (int a = 0; a < 4; a++) {
            int n = pb * 128 + wn * 64 + a * 16 + g4 * 4;
            float4 bv = *(const float4*)(bproj + n);
#pragma unroll
            for (int b = 0; b < 2; b++) {
                int t = wm * 32 + b * 16 + l15;
                int yy = wy * 8 + (t >> 3) + 4; if (yy >= 96) yy -= 96;
                int xx = wx * 8 + (t & 7) + 4;  if (xx >= 96) xx -= 96;
                floatx4 o = acc[a][b];
                o[0] += bv.x; o[1] += bv.y; o[2] += bv.z; o[3] += bv.w;
                *(floatx4*)(&out[((size_t)b_img * 9216 + yy * 96 + xx) * 384 + n]) = o;
            }
        }
        bp += 49152;
    }
}

// ---------------- launcher ----------------
extern "C" void kernel_launch(void* const* d_in, const int* in_sizes, int n_in,
                              void* d_out, int out_size, void* d_ws, size_t ws_size,
                              hipStream_t stream) {
    const float* query = (const float*)d_in[0];
    const float* skipq = (const float*)d_in[1];
    const float* Wqkv  = (const float*)d_in[2];
    const float* bqkv  = (const float*)d_in[3];
    const float* Wskip = (const float*)d_in[4];
    const float* bskip = (const float*)d_in[5];
    const float* rpb   = (const float*)d_in[6];
    const float* Wproj = (const float*)d_in[7];
    const float* bproj = (const float*)d_in[8];
    float* out = (float*)d_out;

    int M = in_sizes[0] / 384;   // total tokens = 147456 for B=16
    int nwin = M / 64;           // 2304

    char* ws = (char*)d_ws;
    size_t off = 0;
    auto alloc = [&](size_t bytes) -> void* {
        void* p = ws + off;
        off = (off + bytes + 255) & ~(size_t)255;
        return p;
    };
    short* Wt     = (short*)alloc((size_t)1152 * 384 * 2);
    short* WtP    = (short*)alloc((size_t)384 * 384 * 2);
    float* bias64 = (float*)alloc((size_t)12 * 64 * 64 * 4);
    short* kbuf   = (short*)alloc((size_t)M * 384 * 2);
    short* vtbuf  = (short*)alloc((size_t)M * 384 * 2);
    short* qbuf   = (short*)alloc((size_t)M * 384 * 2);
    short* aout   = (short*)alloc((size_t)M * 384 * 2);
    (void)ws_size;

    hipLaunchKernelGGL(prep_wt, dim3(216), dim3(256), 0, stream, Wqkv, Wskip, Wt);
    hipLaunchKernelGGL(prep_wtp, dim3(72), dim3(256), 0, stream, Wproj, WtP);
    hipLaunchKernelGGL(prep_bias, dim3(192), dim3(256), 0, stream, rpb, bias64);
    hipLaunchKernelGGL(gemm_qkv, dim3(nwin, 2), dim3(256), 0, stream,
                       query, skipq, Wt, bqkv, bskip, kbuf, vtbuf, qbuf);
    hipLaunchKernelGGL(attn_kernel, dim3(nwin * 12 / 4), dim3(256), 0, stream,
                       kbuf, vtbuf, qbuf, bias64, aout, nwin * 12);
    hipLaunchKernelGGL(gemm_proj, dim3(nwin), dim3(256), 0, stream,
                       aout, WtP, bproj, out);
}